// Round 2
// baseline (207.417 us; speedup 1.0000x reference)
//
#include <hip/hip_runtime.h>
#include <hip/hip_bf16.h>

// ---------------------------------------------------------------------------
// MonotonicAlignmentSearch R14: kill split-K everywhere. One WAVE owns one
// output tile with full-K register accumulation (conv: 16x32 K=3072, 192
// MFMA/wave; gemm: 32x32 K=1024, 128 MFMA/wave). Zero LDS / zero barriers in
// p2/p3 compute paths; GN stats via per-wave shuffle reduce. GEMM operands
// swapped (A=W^T rows, B=activation rows) so epilogue stores are contiguous
// f16x4/bf16x4 in the consumer layouts. B=2, TT=128, TA=512, H=1024.
// ---------------------------------------------------------------------------

typedef __bf16 bf16_t;
typedef __bf16 bf16x8 __attribute__((ext_vector_type(8)));
typedef __bf16 bf16x4 __attribute__((ext_vector_type(4)));
typedef float  f32x4  __attribute__((ext_vector_type(4)));
typedef _Float16 f16_t;
typedef _Float16 f16x2 __attribute__((ext_vector_type(2)));
typedef _Float16 f16x4 __attribute__((ext_vector_type(4)));

#define EPSV 1e-5f

// ---- workspace offsets (bytes) — no overlays, ~26.3 MB << 256 MB ws -------
#define OFF_TEXTBF   0u          //  524288  bf16 text [256][1024]
#define OFF_AUDIOBF  524288u     // 2097152  bf16 audio [1024][1024]
#define OFF_W1TOP    2621440u    // 2097152  bf16 W1topT [1024 d][1024 h]
#define OFF_W1BOT    4718592u    // 2097152  bf16 W1botT [1024 d][1024 h]
#define OFF_WC1      6815744u    // 6291456  bf16 Wc1 [3][1024][1024]
#define OFF_WC2      13107200u   // 6291456  bf16 Wc2 [3][1024][1024] (g-scaled)
#define OFF_TP       19398656u   //  524288  f16 tp [256 bt][1024 d] (bias folded)
#define OFF_W2F      19922944u   //    2048  f16 w2 [1024]
#define OFF_APT      20447232u   // 2097152  f16 apT4 [256 hq][1024 ba][4]
#define OFF_XP0      22544384u   //  532480  bf16 xp0 [2][130][1024]
#define OFF_XP1      23076864u   //  532480  bf16 xp1 [2][130][1024] (raw relu)
#define OFF_Y2       23609344u   //  524288  bf16 y2 [256][1024] (pre-GN2)
#define OFF_BST1     24133632u   //    4096  f32 bstat1 [512][2] (conv1 partials)
#define OFF_BST2     24137728u   //    4096  f32 bstat2 [512][2] (conv2 partials)
#define OFF_LP       24141824u   // 2097152  f32 lp [4 hc][256 bt][512 a]
#define OFF_SG       26238976u   //   12288  f32 Sg [1024][3]  (sum_c w2*g)
#define OFF_SB       26251264u   //   12288  f32 Sb [1024][3]  (sum_c w2*beta)
#define OFF_SGF      26263552u   //    4096  f32 SgF [1024] (full tap sum)
#define OFF_SBF      26267648u   //    4096  f32 SbF [1024]

// ---------------------------------------------------------------------------
// prep: [0,1280) cvt activations; [1280,3328) w1 transpose-cast;
// [3328,5376) conv-weight cvt (wc2 g-scaled + Sg/Sb/SgF/SbF sums);
// 5376: zero pads + w2->f16.
// ---------------------------------------------------------------------------
__global__ __launch_bounds__(256) void prep_k(
    const float* __restrict__ text, const float* __restrict__ audio,
    const float* __restrict__ w1,
    const float* __restrict__ w1c, const float* __restrict__ w2c,
    const float* __restrict__ w2,
    const float* __restrict__ g1, const float* __restrict__ b1g,
    bf16_t* __restrict__ text_bf, bf16_t* __restrict__ xp0,
    bf16_t* __restrict__ audio_bf,
    bf16_t* __restrict__ topT, bf16_t* __restrict__ botT,
    bf16_t* __restrict__ wc1, bf16_t* __restrict__ wc2,
    bf16_t* __restrict__ xp1, f16_t* __restrict__ w2f,
    float* __restrict__ Sg, float* __restrict__ Sb,
    float* __restrict__ SgF, float* __restrict__ SbF)
{
    __shared__ float tile[32][33];
    const int bid = blockIdx.x;
    if (bid < 1280) {
        const int e = (bid * 256 + threadIdx.x) * 4;   // 1310720 total
        if (e < 262144) {
            float4 v = *(const float4*)&text[e];
            bf16x4 o; o[0] = (bf16_t)v.x; o[1] = (bf16_t)v.y; o[2] = (bf16_t)v.z; o[3] = (bf16_t)v.w;
            *(bf16x4*)&text_bf[e] = o;
            const int bt = e >> 10, h = e & 1023;
            const int b = bt >> 7, t = bt & 127;
            *(bf16x4*)&xp0[(size_t)(b * 130 + 1 + t) * 1024 + h] = o;
        } else {
            const int ea = e - 262144;
            float4 v = *(const float4*)&audio[ea];
            bf16x4 o; o[0] = (bf16_t)v.x; o[1] = (bf16_t)v.y; o[2] = (bf16_t)v.z; o[3] = (bf16_t)v.w;
            *(bf16x4*)&audio_bf[ea] = o;
        }
    } else if (bid < 3328) {
        const int b2 = bid - 1280;
        const int bx = b2 & 31, by = b2 >> 5;          // (32, 64)
        const int tx = threadIdx.x & 31, ty = threadIdx.x >> 5;
        #pragma unroll
        for (int j = 0; j < 4; ++j)
            tile[ty + j * 8][tx] = w1[(size_t)(by * 32 + ty + j * 8) * 1024 + bx * 32 + tx];
        __syncthreads();
        bf16_t* out = (by < 32) ? topT : botT;
        const int hbase = (by & 31) * 32;
        #pragma unroll
        for (int j = 0; j < 4; ++j) {
            const int d = bx * 32 + ty + j * 8;
            out[(size_t)d * 1024 + hbase + tx] = (bf16_t)tile[tx][ty + j * 8];
        }
    } else if (bid < 5376) {
        int b2 = bid - 3328;
        const int is2 = (b2 >= 1024) ? 1 : 0;
        const float* w = is2 ? w2c : w1c;
        bf16_t* wc = is2 ? wc2 : wc1;
        b2 &= 1023;
        const int o = b2, i4 = threadIdx.x;            // one block per out-chan
        const float* src = w + (size_t)o * 3072 + i4 * 12;
        float4 v0 = *(const float4*)&src[0];
        float4 v1 = *(const float4*)&src[4];
        float4 v2 = *(const float4*)&src[8];
        const float f[12] = {v0.x, v0.y, v0.z, v0.w, v1.x, v1.y, v1.z, v1.w, v2.x, v2.y, v2.z, v2.w};
        float g4[4] = {1.f, 1.f, 1.f, 1.f}, bb4[4] = {0.f, 0.f, 0.f, 0.f};
        if (is2) {
            float4 gv = *(const float4*)&g1[i4 * 4];
            float4 bv = *(const float4*)&b1g[i4 * 4];
            g4[0] = gv.x; g4[1] = gv.y; g4[2] = gv.z; g4[3] = gv.w;
            bb4[0] = bv.x; bb4[1] = bv.y; bb4[2] = bv.z; bb4[3] = bv.w;
        }
        float sgr[3] = {0.f, 0.f, 0.f}, sbr[3] = {0.f, 0.f, 0.f};
        #pragma unroll
        for (int r = 0; r < 3; ++r) {
            bf16x4 o4;
            #pragma unroll
            for (int j = 0; j < 4; ++j) {
                const float wv = f[j * 3 + r];
                const float ws = wv * g4[j];
                sgr[r] += ws;
                sbr[r] += wv * bb4[j];
                o4[j] = (bf16_t)(is2 ? ws : wv);
            }
            *(bf16x4*)&wc[(size_t)r * 1048576 + (size_t)o * 1024 + i4 * 4] = o4;
        }
        if (is2) {
            #pragma unroll
            for (int off = 32; off > 0; off >>= 1) {
                #pragma unroll
                for (int r = 0; r < 3; ++r) {
                    sgr[r] += __shfl_xor(sgr[r], off);
                    sbr[r] += __shfl_xor(sbr[r], off);
                }
            }
            float* red = &tile[0][0];
            const int wid = threadIdx.x >> 6, lane = threadIdx.x & 63;
            if (lane == 0) {
                #pragma unroll
                for (int r = 0; r < 3; ++r) {
                    red[wid * 6 + r] = sgr[r];
                    red[wid * 6 + 3 + r] = sbr[r];
                }
            }
            __syncthreads();
            if (threadIdx.x < 6) {
                const float v = red[threadIdx.x] + red[6 + threadIdx.x]
                              + red[12 + threadIdx.x] + red[18 + threadIdx.x];
                if (threadIdx.x < 3) Sg[o * 3 + threadIdx.x] = v;
                else                 Sb[o * 3 + threadIdx.x - 3] = v;
                red[24 + threadIdx.x] = v;
            }
            __syncthreads();
            if (threadIdx.x == 0)      SgF[o] = red[24] + red[25] + red[26];
            else if (threadIdx.x == 1) SbF[o] = red[27] + red[28] + red[29];
        }
    } else {
        const int tid = threadIdx.x;
        const int rowmap[4] = {0, 129, 130, 259};
        const int f = tid * 16;
        const int r = f >> 10, w = f & 1023;
        bf16x8 z8 = (bf16x8)(bf16_t)0.0f;
        bf16_t* p0 = xp0 + (size_t)rowmap[r] * 1024 + w;
        bf16_t* p1 = xp1 + (size_t)rowmap[r] * 1024 + w;
        *(bf16x8*)p0 = z8; *(bf16x8*)(p0 + 8) = z8;
        *(bf16x8*)p1 = z8; *(bf16x8*)(p1 + 8) = z8;
        float4 wv = *(const float4*)&w2[tid * 4];
        f16x4 wo; wo[0] = (f16_t)wv.x; wo[1] = (f16_t)wv.y; wo[2] = (f16_t)wv.z; wo[3] = (f16_t)wv.w;
        *(f16x4*)&w2f[tid * 4] = wo;
    }
}

// ---------------------------------------------------------------------------
// helpers
// ---------------------------------------------------------------------------
__device__ __forceinline__ float wave_red_add(float v) {
    #pragma unroll
    for (int off = 32; off > 0; off >>= 1) v += __shfl_xor(v, off);
    return v;
}

// Per-wave conv MFMA: 16 chans (m0..m0+15) x 32 bt (tbase..+31), full K=3072.
// Frag layout (verified): C[m][n] with m=(l>>4)*4+r (A=Wc rows), n=l&15 (+16
// for acc1) (B=xp rows).
__device__ __forceinline__ void conv_mfma(
    const bf16_t* __restrict__ Wc, const bf16_t* __restrict__ xp,
    int m0, int b, int tbase, int l, f32x4& acc0, f32x4& acc1)
{
    const int lm = l & 15, lk = (l >> 4) * 8;
    const bf16_t* aq = Wc + (size_t)(m0 + lm) * 1024 + lk;
    const bf16_t* bq = xp + (size_t)(b * 130 + tbase + lm) * 1024 + lk;
    #pragma unroll
    for (int r = 0; r < 3; ++r) {
        const bf16_t* ar = aq + (size_t)r * 1048576;
        const bf16_t* br = bq + (size_t)r * 1024;
        #pragma unroll 4
        for (int kk = 0; kk < 1024; kk += 32) {
            bf16x8 af = *(const bf16x8*)(ar + kk);
            bf16x8 bf0 = *(const bf16x8*)(br + kk);
            bf16x8 bf1 = *(const bf16x8*)(br + 16384 + kk);
            acc0 = __builtin_amdgcn_mfma_f32_16x16x32_bf16(af, bf0, acc0, 0, 0, 0);
            acc1 = __builtin_amdgcn_mfma_f32_16x16x32_bf16(af, bf1, acc1, 0, 0, 0);
        }
    }
}

// ---------------------------------------------------------------------------
// P2: blocks [0,128) conv1 (4 wave-tiles/block); [128,192) tp gemm;
//     [192,448) ap gemm. 256 threads, no LDS, no barriers.
// ---------------------------------------------------------------------------
__global__ __launch_bounds__(256) void p2_k(
    const bf16_t* __restrict__ wc1, const bf16_t* __restrict__ xp0,
    const float* __restrict__ d_b1, bf16_t* __restrict__ xp1,
    float* __restrict__ bstat1,
    const bf16_t* __restrict__ text_bf, const bf16_t* __restrict__ w1topT,
    const float* __restrict__ a_b1, f16_t* __restrict__ tp,
    const bf16_t* __restrict__ audio_bf, const bf16_t* __restrict__ w1botT,
    f16_t* __restrict__ apT4)
{
    const int bid = blockIdx.x;
    const int wv = threadIdx.x >> 6, l = threadIdx.x & 63;
    const int lm = l & 15, lh = l >> 4, lk = lh * 8;
    if (bid < 128) {
        const int tile = bid * 4 + wv;
        const int bx = tile >> 6, by = tile & 63;
        const int bt0 = bx * 32, m0 = by * 16;
        const int b = bt0 >> 7, tbase = bt0 & 127;
        f32x4 acc0 = (f32x4)(0.0f), acc1 = (f32x4)(0.0f);
        conv_mfma(wc1, xp0, m0, b, tbase, l, acc0, acc1);
        float4 bv = *(const float4*)&d_b1[m0 + lh * 4];
        float s = 0.f, q = 0.f;
        #pragma unroll
        for (int t2 = 0; t2 < 2; ++t2) {
            f32x4 a = t2 ? acc1 : acc0;
            bf16x4 o4;
            #pragma unroll
            for (int r = 0; r < 4; ++r) {
                float v = fmaxf(a[r] + ((const float*)&bv)[r], 0.f);
                s += v; q += v * v;
                o4[r] = (bf16_t)v;
            }
            const int bt = tbase + t2 * 16 + lm;
            *(bf16x4*)&xp1[(size_t)(b * 130 + 1 + bt) * 1024 + m0 + lh * 4] = o4;
        }
        s = wave_red_add(s); q = wave_red_add(q);
        if (l == 0) { bstat1[tile * 2] = s; bstat1[tile * 2 + 1] = q; }
    } else {
        // gemm: A = W^T rows (h), B = activation rows (bt/a), C[m=h][n=row].
        const bf16_t *At, *Bm;
        int h0, r0, is_tp;
        if (bid < 192) {
            const int unit = (bid - 128) * 4 + wv;       // 256 units: 8 bt x 32 h
            h0 = (unit & 31) * 32; r0 = (unit >> 5) * 32;
            At = w1topT; Bm = text_bf; is_tp = 1;
        } else {
            const int unit = (bid - 192) * 4 + wv;       // 1024 units: 32 a x 32 h
            h0 = (unit & 31) * 32; r0 = (unit >> 5) * 32;
            At = w1botT; Bm = audio_bf; is_tp = 0;
        }
        f32x4 acc[2][2];
        #pragma unroll
        for (int mt = 0; mt < 2; ++mt)
            #pragma unroll
            for (int nt = 0; nt < 2; ++nt) acc[mt][nt] = (f32x4)(0.0f);
        const bf16_t* Ap = At + (size_t)(h0 + lm) * 1024 + lk;
        const bf16_t* Bp = Bm + (size_t)(r0 + lm) * 1024 + lk;
        #pragma unroll 4
        for (int kk = 0; kk < 1024; kk += 32) {
            bf16x8 af0 = *(const bf16x8*)(Ap + kk);
            bf16x8 af1 = *(const bf16x8*)(Ap + 16384 + kk);
            bf16x8 bf0 = *(const bf16x8*)(Bp + kk);
            bf16x8 bf1 = *(const bf16x8*)(Bp + 16384 + kk);
            acc[0][0] = __builtin_amdgcn_mfma_f32_16x16x32_bf16(af0, bf0, acc[0][0], 0, 0, 0);
            acc[0][1] = __builtin_amdgcn_mfma_f32_16x16x32_bf16(af0, bf1, acc[0][1], 0, 0, 0);
            acc[1][0] = __builtin_amdgcn_mfma_f32_16x16x32_bf16(af1, bf0, acc[1][0], 0, 0, 0);
            acc[1][1] = __builtin_amdgcn_mfma_f32_16x16x32_bf16(af1, bf1, acc[1][1], 0, 0, 0);
        }
        if (is_tp) {
            #pragma unroll
            for (int mt = 0; mt < 2; ++mt) {
                const int hb = h0 + mt * 16 + lh * 4;
                float4 bv = *(const float4*)&a_b1[hb];
                #pragma unroll
                for (int nt = 0; nt < 2; ++nt) {
                    const int bt = r0 + nt * 16 + lm;
                    f16x4 v;
                    #pragma unroll
                    for (int r = 0; r < 4; ++r)
                        v[r] = (f16_t)(acc[mt][nt][r] + ((const float*)&bv)[r]);
                    *(f16x4*)&tp[(size_t)bt * 1024 + hb] = v;
                }
            }
        } else {
            #pragma unroll
            for (int mt = 0; mt < 2; ++mt) {
                const int hq = (h0 + mt * 16 + lh * 4) >> 2;
                #pragma unroll
                for (int nt = 0; nt < 2; ++nt) {
                    const int aa = r0 + nt * 16 + lm;
                    const int bb = aa >> 9, al = aa & 511;
                    f16x4 v;
                    #pragma unroll
                    for (int r = 0; r < 4; ++r) v[r] = (f16_t)acc[mt][nt][r];
                    *(f16x4*)&apT4[((size_t)hq * 1024 + bb * 512 + al) * 4] = v;
                }
            }
        }
    }
}

// ---------------------------------------------------------------------------
// P3: blocks [0,128) conv2 wave-tiles (GN1 folded, per-wave stat reduce);
//     blocks [128,640) logits (a split in halves of 256). No LDS.
// ---------------------------------------------------------------------------
__device__ __forceinline__ float dot2_acc(f16x2 x, f16x2 w, float acc) {
#if __has_builtin(__builtin_amdgcn_fdot2)
    return __builtin_amdgcn_fdot2(x, w, acc, false);
#else
    return acc + (float)x[0] * (float)w[0] + (float)x[1] * (float)w[1];
#endif
}

__global__ __launch_bounds__(256) void p3_k(
    const bf16_t* __restrict__ wc2, const bf16_t* __restrict__ xp1,
    const float* __restrict__ d_b2, bf16_t* __restrict__ y2,
    float* __restrict__ bstat2, const float* __restrict__ bstat1,
    const float* __restrict__ SgF, const float* __restrict__ SbF,
    const float* __restrict__ Sg3, const float* __restrict__ Sb3,
    const f16_t* __restrict__ tp, const f16_t* __restrict__ apT4,
    const f16_t* __restrict__ w2f, float* __restrict__ lp)
{
    const int bid = blockIdx.x;
    const int tid = threadIdx.x;
    if (bid < 128) {
        const int wv = tid >> 6, l = tid & 63;
        const int lm = l & 15, lh = l >> 4;
        const int tile = bid * 4 + wv;
        const int bx = tile >> 6, by = tile & 63;
        const int bt0 = bx * 32, m0 = by * 16;
        const int b = bt0 >> 7, tbase = bt0 & 127;
        f32x4 acc0 = (f32x4)(0.0f), acc1 = (f32x4)(0.0f);
        conv_mfma(wc2, xp1, m0, b, tbase, l, acc0, acc1);
        // per-wave GN1 stat reduce (256 (s,q) pairs = 128 float4)
        float s0, q0;
        {
            const float4* bp = (const float4*)bstat1 + (size_t)b * 128;
            float4 p0 = bp[l * 2], p1 = bp[l * 2 + 1];
            s0 = p0.x + p0.z + p1.x + p1.z;
            q0 = p0.y + p0.w + p1.y + p1.w;
        }
        s0 = wave_red_add(s0); q0 = wave_red_add(q0);
        const float mu = s0 * (1.f / 131072.f);
        const float rsig = rsqrtf(q0 * (1.f / 131072.f) - mu * mu + EPSV);
        float4 bv = *(const float4*)&d_b2[m0 + lh * 4];
        float4 gF = *(const float4*)&SgF[m0 + lh * 4];
        float4 bF = *(const float4*)&SbF[m0 + lh * 4];
        float s = 0.f, q = 0.f;
        #pragma unroll
        for (int t2 = 0; t2 < 2; ++t2) {
            f32x4 a = t2 ? acc1 : acc0;
            const int bt = tbase + t2 * 16 + lm;
            const bool e0 = (bt == 0), e1 = (bt == 127);
            bf16x4 o4;
            #pragma unroll
            for (int r = 0; r < 4; ++r) {
                const int o = m0 + lh * 4 + r;
                float sg = ((const float*)&gF)[r], sb = ((const float*)&bF)[r];
                if (e0) { sg -= Sg3[o * 3];     sb -= Sb3[o * 3]; }
                if (e1) { sg -= Sg3[o * 3 + 2]; sb -= Sb3[o * 3 + 2]; }
                float v = fmaxf(rsig * a[r] + sb - mu * rsig * sg + ((const float*)&bv)[r], 0.f);
                s += v; q += v * v;
                o4[r] = (bf16_t)v;
            }
            *(bf16x4*)&y2[(size_t)(b * 128 + bt) * 1024 + m0 + lh * 4] = o4;
        }
        s = wave_red_add(s); q = wave_red_add(q);
        if (l == 0) { bstat2[tile * 2] = s; bstat2[tile * 2 + 1] = q; }
    } else {
        const int lb = bid - 128;                       // 512 blocks
        const int hc = lb >> 7, btp = (lb >> 1) & 63, half = lb & 1;
        const int bt0 = btp * 4;
        const int b = bt0 >> 7;
        const int a = half * 256 + tid;
        const f16_t* tpr = tp + (size_t)bt0 * 1024 + hc * 256;   // wave-uniform
        const f16_t* w2r = w2f + hc * 256;
        const f16_t* apc = apT4 + ((size_t)(hc * 64) * 1024 + b * 512 + a) * 4;
        float acc[4] = {0.f, 0.f, 0.f, 0.f};
        const f16x2 zero = (f16x2)(f16_t)0.0f;
        #pragma unroll 2
        for (int hq = 0; hq < 64; hq += 2) {                    // 8 h per iter
            f16x4 a0 = *(const f16x4*)(apc + (size_t)hq * 4096);
            f16x4 a1 = *(const f16x4*)(apc + (size_t)(hq + 1) * 4096);
            f16x4 w0 = *(const f16x4*)&w2r[hq * 4];
            f16x4 w1 = *(const f16x4*)&w2r[hq * 4 + 4];
            #pragma unroll
            for (int r = 0; r < 4; ++r) {
                f16x4 t0 = *(const f16x4*)&tpr[r * 1024 + hq * 4];
                f16x4 t1 = *(const f16x4*)&tpr[r * 1024 + hq * 4 + 4];
                f16x2 p;
                p = __builtin_elementwise_max((f16x2){t0[0] + a0[0], t0[1] + a0[1]}, zero);
                acc[r] = dot2_acc(p, (f16x2){w0[0], w0[1]}, acc[r]);
                p = __builtin_elementwise_max((f16x2){t0[2] + a0[2], t0[3] + a0[3]}, zero);
                acc[r] = dot2_acc(p, (f16x2){w0[2], w0[3]}, acc[r]);
                p = __builtin_elementwise_max((f16x2){t1[0] + a1[0], t1[1] + a1[1]}, zero);
                acc[r] = dot2_acc(p, (f16x2){w1[0], w1[1]}, acc[r]);
                p = __builtin_elementwise_max((f16x2){t1[2] + a1[2], t1[3] + a1[3]}, zero);
                acc[r] = dot2_acc(p, (f16x2){w1[2], w1[3]}, acc[r]);
            }
        }
        float* dst = lp + (size_t)(hc * 256 + bt0) * 512 + a;
        #pragma unroll
        for (int r = 0; r < 4; ++r) dst[(size_t)r * 512] = acc[r];
    }
}

// reduce 256 (s,q) pairs for batch b from bstat (block-level, 512 threads).
__device__ __forceinline__ void reduce_bstat(
    const float* __restrict__ bstat, int b, int tid,
    float* sr, float* sq, float& mu, float& rsig)
{
    const int lane = tid & 63, wid = tid >> 6;
    float s = 0.f, q = 0.f;
    if (tid < 256) {
        float2 v = ((const float2*)bstat)[b * 256 + tid];
        s = v.x; q = v.y;
    }
    #pragma unroll
    for (int off = 32; off > 0; off >>= 1) {
        s += __shfl_xor(s, off);
        q += __shfl_xor(q, off);
    }
    if (lane == 0) { sr[wid] = s; sq[wid] = q; }
    __syncthreads();
    float ts = 0.f, tq = 0.f;
    #pragma unroll
    for (int i = 0; i < 8; ++i) { ts += sr[i]; tq += sq[i]; }
    const float cnt = 131072.f;
    mu = ts / cnt;
    const float var = tq / cnt - mu * mu;
    rsig = rsqrtf(var + EPSV);
}

// ---------------------------------------------------------------------------
// combine: blocks [0,256): sum lp chunks + bias + monotonic, softmax -> out.
//          blocks [256,288): conv3 + GN2 (reduced from bstat2) + softplus.
// ---------------------------------------------------------------------------
__global__ __launch_bounds__(512) void combine_k(
    const float* __restrict__ lp, const float* __restrict__ b2,
    const bf16_t* __restrict__ y2, const float* __restrict__ bstat2,
    const float* __restrict__ g, const float* __restrict__ bet,
    const float* __restrict__ w3, const float* __restrict__ b3,
    float* __restrict__ out)
{
    __shared__ float redm[8], redsum[8];
    const int bid = blockIdx.x;
    const int tid = threadIdx.x;
    if (bid < 256) {
        const int bt = bid, t = bt & 127;
        const int a = tid;
        const int lane = a & 63, wid = a >> 6;
        const size_t base = (size_t)bt * 512 + a;
        float v = lp[base] + lp[131072 + base] + lp[262144 + base] + lp[393216 + base];
        v += b2[0] - 0.1f * fabsf((float)a - 4.0f * (float)t);
        float m = v;
        #pragma unroll
        for (int off = 32; off > 0; off >>= 1) m = fmaxf(m, __shfl_xor(m, off));
        if (lane == 0) redm[wid] = m;
        __syncthreads();
        float M = redm[0];
        #pragma unroll
        for (int i = 1; i < 8; ++i) M = fmaxf(M, redm[i]);
        const float e = expf(v - M);
        float s = e;
        #pragma unroll
        for (int off = 32; off > 0; off >>= 1) s += __shfl_xor(s, off);
        if (lane == 0) redsum[wid] = s;
        __syncthreads();
        float S = redsum[0];
        #pragma unroll
        for (int i = 1; i < 8; ++i) S += redsum[i];
        out[(size_t)bt * 512 + a] = e * (1.0f / S);
    } else {
        // conv3 + GN2-fold + softplus; mu/var reduced from conv2 partials.
        const int cb = bid - 256;              // 0..31, bt [cb*8, cb*8+8)
        const int b = (cb * 8) >> 7;
        float mu, rsig;
        reduce_bstat(bstat2, b, tid, redm, redsum, mu, rsig);
        const int lane = tid & 63, w = tid >> 6;
        const int bt = cb * 8 + w;
        const bf16_t* row = y2 + (size_t)bt * 1024 + lane * 16;
        float s1 = 0.f, s2 = 0.f, s3 = 0.f;
        #pragma unroll
        for (int c = 0; c < 2; ++c) {
            bf16x8 yv = *(const bf16x8*)(row + c * 8);
            #pragma unroll
            for (int j = 0; j < 8; ++j) {
                const int i = lane * 16 + c * 8 + j;
                const float gw = g[i] * w3[i];
                s1 += gw * (float)yv[j];
                s2 += gw;
                s3 += bet[i] * w3[i];
            }
        }
        #pragma unroll
        for (int off = 32; off > 0; off >>= 1) {
            s1 += __shfl_xor(s1, off);
            s2 += __shfl_xor(s2, off);
            s3 += __shfl_xor(s3, off);
        }
        if (lane == 0) {
            const float t = rsig * (s1 - mu * s2) + s3 + b3[0];
            out[131072 + bt] = fmaxf(t, 0.f) + log1pf(expf(-fabsf(t)));
        }
    }
}

extern "C" void kernel_launch(void* const* d_in, const int* in_sizes, int n_in,
                              void* d_out, int out_size, void* d_ws, size_t ws_size,
                              hipStream_t stream) {
    const float* text   = (const float*)d_in[0];
    const float* audio  = (const float*)d_in[1];
    const float* a_w1   = (const float*)d_in[2];
    const float* a_b1   = (const float*)d_in[3];
    const float* a_w2   = (const float*)d_in[4];
    const float* a_b2   = (const float*)d_in[5];
    const float* d_w1   = (const float*)d_in[6];
    const float* d_b1   = (const float*)d_in[7];
    const float* gn1_g  = (const float*)d_in[8];
    const float* gn1_b  = (const float*)d_in[9];
    const float* d_w2   = (const float*)d_in[10];
    const float* d_b2   = (const float*)d_in[11];
    const float* gn2_g  = (const float*)d_in[12];
    const float* gn2_b  = (const float*)d_in[13];
    const float* d_w3   = (const float*)d_in[14];
    const float* d_b3   = (const float*)d_in[15];

    char* ws = (char*)d_ws;
    float* outf = (float*)d_out;

    bf16_t* text_bf  = (bf16_t*)(ws + OFF_TEXTBF);
    bf16_t* audio_bf = (bf16_t*)(ws + OFF_AUDIOBF);
    bf16_t* w1topT   = (bf16_t*)(ws + OFF_W1TOP);
    bf16_t* w1botT   = (bf16_t*)(ws + OFF_W1BOT);
    bf16_t* wc1      = (bf16_t*)(ws + OFF_WC1);
    bf16_t* wc2      = (bf16_t*)(ws + OFF_WC2);
    f16_t*  tp       = (f16_t*) (ws + OFF_TP);
    f16_t*  w2f      = (f16_t*) (ws + OFF_W2F);
    f16_t*  apT4     = (f16_t*) (ws + OFF_APT);
    bf16_t* xp0      = (bf16_t*)(ws + OFF_XP0);
    bf16_t* xp1      = (bf16_t*)(ws + OFF_XP1);
    bf16_t* y2       = (bf16_t*)(ws + OFF_Y2);
    float*  bstat1   = (float*) (ws + OFF_BST1);
    float*  bstat2   = (float*) (ws + OFF_BST2);
    float*  lp       = (float*) (ws + OFF_LP);
    float*  Sg3     = (float*) (ws + OFF_SG);
    float*  Sb3     = (float*) (ws + OFF_SB);
    float*  SgFp    = (float*) (ws + OFF_SGF);
    float*  SbFp    = (float*) (ws + OFF_SBF);

    // 1: prep (cvt activations, w1 transpose, conv weights + sums, pads, w2f)
    prep_k<<<dim3(5377), 256, 0, stream>>>(text, audio, a_w1, d_w1, d_w2, a_w2,
                                           gn1_g, gn1_b,
                                           text_bf, xp0, audio_bf, w1topT, w1botT,
                                           wc1, wc2, xp1, w2f, Sg3, Sb3,
                                           SgFp, SbFp);
    // 2: conv1 wave-tiles ∥ tp gemm ∥ ap gemm (448 blocks x 256 thr, no LDS)
    p2_k<<<dim3(448), 256, 0, stream>>>(wc1, xp0, d_b1, xp1, bstat1,
                                        text_bf, w1topT, a_b1, tp,
                                        audio_bf, w1botT, apT4);
    // 3: conv2 (GN1 folded) ∥ logits partials (640 blocks x 256 thr)
    p3_k<<<dim3(640), 256, 0, stream>>>(wc2, xp1, d_b2, y2, bstat2, bstat1,
                                        SgFp, SbFp, Sg3, Sb3, tp, apT4, w2f, lp);
    // 4: combine+softmax -> alignment; conv3+GN2(reduced)+softplus -> durations
    combine_k<<<dim3(288), 512, 0, stream>>>(lp, a_b2, y2, bstat2,
                                             gn2_g, gn2_b, d_w3, d_b3, outf);
}

// Round 3
// 205.997 us; speedup vs baseline: 1.0069x; 1.0069x over previous
//
#include <hip/hip_runtime.h>
#include <hip/hip_bf16.h>

// ---------------------------------------------------------------------------
// MonotonicAlignmentSearch R15: R14 structure (wave-owns-tile, no LDS, no
// barriers) + explicit software-pipelined register prefetch (depth 6 conv /
// 4 gemm+logits, fully unrolled => static queue slots). R14's counters showed
// latency-serialized loads (VGPR=40, MfmaUtil 2.9%, 402 GB/s): compiler kept
// ~0 loads in flight. This version keeps 12-18 outstanding 1KB loads/wave.
// B=2, TT=128, TA=512, H=1024.
// ---------------------------------------------------------------------------

typedef __bf16 bf16_t;
typedef __bf16 bf16x8 __attribute__((ext_vector_type(8)));
typedef __bf16 bf16x4 __attribute__((ext_vector_type(4)));
typedef float  f32x4  __attribute__((ext_vector_type(4)));
typedef _Float16 f16_t;
typedef _Float16 f16x2 __attribute__((ext_vector_type(2)));
typedef _Float16 f16x4 __attribute__((ext_vector_type(4)));

#define EPSV 1e-5f

// ---- workspace offsets (bytes) — no overlays, ~26.3 MB << 256 MB ws -------
#define OFF_TEXTBF   0u          //  524288  bf16 text [256][1024]
#define OFF_AUDIOBF  524288u     // 2097152  bf16 audio [1024][1024]
#define OFF_W1TOP    2621440u    // 2097152  bf16 W1topT [1024 d][1024 h]
#define OFF_W1BOT    4718592u    // 2097152  bf16 W1botT [1024 d][1024 h]
#define OFF_WC1      6815744u    // 6291456  bf16 Wc1 [3][1024][1024]
#define OFF_WC2      13107200u   // 6291456  bf16 Wc2 [3][1024][1024] (g-scaled)
#define OFF_TP       19398656u   //  524288  f16 tp [256 bt][1024 d] (bias folded)
#define OFF_W2F      19922944u   //    2048  f16 w2 [1024]
#define OFF_APT      20447232u   // 2097152  f16 apT4 [256 hq][1024 ba][4]
#define OFF_XP0      22544384u   //  532480  bf16 xp0 [2][130][1024]
#define OFF_XP1      23076864u   //  532480  bf16 xp1 [2][130][1024] (raw relu)
#define OFF_Y2       23609344u   //  524288  bf16 y2 [256][1024] (pre-GN2)
#define OFF_BST1     24133632u   //    4096  f32 bstat1 [512][2] (conv1 partials)
#define OFF_BST2     24137728u   //    4096  f32 bstat2 [512][2] (conv2 partials)
#define OFF_LP       24141824u   // 2097152  f32 lp [4 hc][256 bt][512 a]
#define OFF_SG       26238976u   //   12288  f32 Sg [1024][3]  (sum_c w2*g)
#define OFF_SB       26251264u   //   12288  f32 Sb [1024][3]  (sum_c w2*beta)
#define OFF_SGF      26263552u   //    4096  f32 SgF [1024] (full tap sum)
#define OFF_SBF      26267648u   //    4096  f32 SbF [1024]

// ---------------------------------------------------------------------------
// prep: [0,1280) cvt activations; [1280,3328) w1 transpose-cast;
// [3328,5376) conv-weight cvt (wc2 g-scaled + Sg/Sb/SgF/SbF sums);
// 5376: zero pads + w2->f16.
// ---------------------------------------------------------------------------
__global__ __launch_bounds__(256) void prep_k(
    const float* __restrict__ text, const float* __restrict__ audio,
    const float* __restrict__ w1,
    const float* __restrict__ w1c, const float* __restrict__ w2c,
    const float* __restrict__ w2,
    const float* __restrict__ g1, const float* __restrict__ b1g,
    bf16_t* __restrict__ text_bf, bf16_t* __restrict__ xp0,
    bf16_t* __restrict__ audio_bf,
    bf16_t* __restrict__ topT, bf16_t* __restrict__ botT,
    bf16_t* __restrict__ wc1, bf16_t* __restrict__ wc2,
    bf16_t* __restrict__ xp1, f16_t* __restrict__ w2f,
    float* __restrict__ Sg, float* __restrict__ Sb,
    float* __restrict__ SgF, float* __restrict__ SbF)
{
    __shared__ float tile[32][33];
    const int bid = blockIdx.x;
    if (bid < 1280) {
        const int e = (bid * 256 + threadIdx.x) * 4;   // 1310720 total
        if (e < 262144) {
            float4 v = *(const float4*)&text[e];
            bf16x4 o; o[0] = (bf16_t)v.x; o[1] = (bf16_t)v.y; o[2] = (bf16_t)v.z; o[3] = (bf16_t)v.w;
            *(bf16x4*)&text_bf[e] = o;
            const int bt = e >> 10, h = e & 1023;
            const int b = bt >> 7, t = bt & 127;
            *(bf16x4*)&xp0[(size_t)(b * 130 + 1 + t) * 1024 + h] = o;
        } else {
            const int ea = e - 262144;
            float4 v = *(const float4*)&audio[ea];
            bf16x4 o; o[0] = (bf16_t)v.x; o[1] = (bf16_t)v.y; o[2] = (bf16_t)v.z; o[3] = (bf16_t)v.w;
            *(bf16x4*)&audio_bf[ea] = o;
        }
    } else if (bid < 3328) {
        const int b2 = bid - 1280;
        const int bx = b2 & 31, by = b2 >> 5;          // (32, 64)
        const int tx = threadIdx.x & 31, ty = threadIdx.x >> 5;
        #pragma unroll
        for (int j = 0; j < 4; ++j)
            tile[ty + j * 8][tx] = w1[(size_t)(by * 32 + ty + j * 8) * 1024 + bx * 32 + tx];
        __syncthreads();
        bf16_t* out = (by < 32) ? topT : botT;
        const int hbase = (by & 31) * 32;
        #pragma unroll
        for (int j = 0; j < 4; ++j) {
            const int d = bx * 32 + ty + j * 8;
            out[(size_t)d * 1024 + hbase + tx] = (bf16_t)tile[tx][ty + j * 8];
        }
    } else if (bid < 5376) {
        int b2 = bid - 3328;
        const int is2 = (b2 >= 1024) ? 1 : 0;
        const float* w = is2 ? w2c : w1c;
        bf16_t* wc = is2 ? wc2 : wc1;
        b2 &= 1023;
        const int o = b2, i4 = threadIdx.x;            // one block per out-chan
        const float* src = w + (size_t)o * 3072 + i4 * 12;
        float4 v0 = *(const float4*)&src[0];
        float4 v1 = *(const float4*)&src[4];
        float4 v2 = *(const float4*)&src[8];
        const float f[12] = {v0.x, v0.y, v0.z, v0.w, v1.x, v1.y, v1.z, v1.w, v2.x, v2.y, v2.z, v2.w};
        float g4[4] = {1.f, 1.f, 1.f, 1.f}, bb4[4] = {0.f, 0.f, 0.f, 0.f};
        if (is2) {
            float4 gv = *(const float4*)&g1[i4 * 4];
            float4 bv = *(const float4*)&b1g[i4 * 4];
            g4[0] = gv.x; g4[1] = gv.y; g4[2] = gv.z; g4[3] = gv.w;
            bb4[0] = bv.x; bb4[1] = bv.y; bb4[2] = bv.z; bb4[3] = bv.w;
        }
        float sgr[3] = {0.f, 0.f, 0.f}, sbr[3] = {0.f, 0.f, 0.f};
        #pragma unroll
        for (int r = 0; r < 3; ++r) {
            bf16x4 o4;
            #pragma unroll
            for (int j = 0; j < 4; ++j) {
                const float wv = f[j * 3 + r];
                const float ws = wv * g4[j];
                sgr[r] += ws;
                sbr[r] += wv * bb4[j];
                o4[j] = (bf16_t)(is2 ? ws : wv);
            }
            *(bf16x4*)&wc[(size_t)r * 1048576 + (size_t)o * 1024 + i4 * 4] = o4;
        }
        if (is2) {
            #pragma unroll
            for (int off = 32; off > 0; off >>= 1) {
                #pragma unroll
                for (int r = 0; r < 3; ++r) {
                    sgr[r] += __shfl_xor(sgr[r], off);
                    sbr[r] += __shfl_xor(sbr[r], off);
                }
            }
            float* red = &tile[0][0];
            const int wid = threadIdx.x >> 6, lane = threadIdx.x & 63;
            if (lane == 0) {
                #pragma unroll
                for (int r = 0; r < 3; ++r) {
                    red[wid * 6 + r] = sgr[r];
                    red[wid * 6 + 3 + r] = sbr[r];
                }
            }
            __syncthreads();
            if (threadIdx.x < 6) {
                const float v = red[threadIdx.x] + red[6 + threadIdx.x]
                              + red[12 + threadIdx.x] + red[18 + threadIdx.x];
                if (threadIdx.x < 3) Sg[o * 3 + threadIdx.x] = v;
                else                 Sb[o * 3 + threadIdx.x - 3] = v;
                red[24 + threadIdx.x] = v;
            }
            __syncthreads();
            if (threadIdx.x == 0)      SgF[o] = red[24] + red[25] + red[26];
            else if (threadIdx.x == 1) SbF[o] = red[27] + red[28] + red[29];
        }
    } else {
        const int tid = threadIdx.x;
        const int rowmap[4] = {0, 129, 130, 259};
        const int f = tid * 16;
        const int r = f >> 10, w = f & 1023;
        bf16x8 z8 = (bf16x8)(bf16_t)0.0f;
        bf16_t* p0 = xp0 + (size_t)rowmap[r] * 1024 + w;
        bf16_t* p1 = xp1 + (size_t)rowmap[r] * 1024 + w;
        *(bf16x8*)p0 = z8; *(bf16x8*)(p0 + 8) = z8;
        *(bf16x8*)p1 = z8; *(bf16x8*)(p1 + 8) = z8;
        float4 wv = *(const float4*)&w2[tid * 4];
        f16x4 wo; wo[0] = (f16_t)wv.x; wo[1] = (f16_t)wv.y; wo[2] = (f16_t)wv.z; wo[3] = (f16_t)wv.w;
        *(f16x4*)&w2f[tid * 4] = wo;
    }
}

// ---------------------------------------------------------------------------
// helpers
// ---------------------------------------------------------------------------
__device__ __forceinline__ float wave_red_add(float v) {
    #pragma unroll
    for (int off = 32; off > 0; off >>= 1) v += __shfl_xor(v, off);
    return v;
}

// Per-wave conv MFMA, software-pipelined (queue depth 6 => 18 loads in
// flight). 16 chans x 32 bt, full K=3072 flattened to 96 k-chunks.
__device__ __forceinline__ void conv_mfma(
    const bf16_t* __restrict__ Wc, const bf16_t* __restrict__ xp,
    int m0, int b, int tbase, int l, f32x4& acc0, f32x4& acc1)
{
    const int lm = l & 15, lk = (l >> 4) * 8;
    const bf16_t* aq = Wc + (size_t)(m0 + lm) * 1024 + lk;
    const bf16_t* bq = xp + (size_t)(b * 130 + tbase + lm) * 1024 + lk;
#define C_LA(it)  (*(const bf16x8*)(aq + (size_t)((it) >> 5) * 1048576 + ((it) & 31) * 32))
#define C_LB0(it) (*(const bf16x8*)(bq + (size_t)((it) >> 5) * 1024 + ((it) & 31) * 32))
#define C_LB1(it) (*(const bf16x8*)(bq + (size_t)((it) >> 5) * 1024 + 16384 + ((it) & 31) * 32))
    constexpr int PF = 6;
    bf16x8 sa[PF], s0[PF], s1[PF];
    #pragma unroll
    for (int it = 0; it < PF; ++it) { sa[it] = C_LA(it); s0[it] = C_LB0(it); s1[it] = C_LB1(it); }
    #pragma unroll
    for (int it = 0; it < 96; ++it) {
        const int sl = it % PF;
        acc0 = __builtin_amdgcn_mfma_f32_16x16x32_bf16(sa[sl], s0[sl], acc0, 0, 0, 0);
        acc1 = __builtin_amdgcn_mfma_f32_16x16x32_bf16(sa[sl], s1[sl], acc1, 0, 0, 0);
        const int nx = it + PF;
        if (nx < 96) { sa[sl] = C_LA(nx); s0[sl] = C_LB0(nx); s1[sl] = C_LB1(nx); }
    }
#undef C_LA
#undef C_LB0
#undef C_LB1
}

// ---------------------------------------------------------------------------
// P2: blocks [0,128) conv1 (4 wave-tiles/block); [128,192) tp gemm;
//     [192,448) ap gemm. 256 threads, no LDS, no barriers.
// ---------------------------------------------------------------------------
__global__ __launch_bounds__(256) void p2_k(
    const bf16_t* __restrict__ wc1, const bf16_t* __restrict__ xp0,
    const float* __restrict__ d_b1, bf16_t* __restrict__ xp1,
    float* __restrict__ bstat1,
    const bf16_t* __restrict__ text_bf, const bf16_t* __restrict__ w1topT,
    const float* __restrict__ a_b1, f16_t* __restrict__ tp,
    const bf16_t* __restrict__ audio_bf, const bf16_t* __restrict__ w1botT,
    f16_t* __restrict__ apT4)
{
    const int bid = blockIdx.x;
    const int wv = threadIdx.x >> 6, l = threadIdx.x & 63;
    const int lm = l & 15, lh = l >> 4, lk = lh * 8;
    if (bid < 128) {
        const int tile = bid * 4 + wv;
        const int bx = tile >> 6, by = tile & 63;
        const int bt0 = bx * 32, m0 = by * 16;
        const int b = bt0 >> 7, tbase = bt0 & 127;
        f32x4 acc0 = (f32x4)(0.0f), acc1 = (f32x4)(0.0f);
        conv_mfma(wc1, xp0, m0, b, tbase, l, acc0, acc1);
        float4 bv = *(const float4*)&d_b1[m0 + lh * 4];
        float s = 0.f, q = 0.f;
        #pragma unroll
        for (int t2 = 0; t2 < 2; ++t2) {
            f32x4 a = t2 ? acc1 : acc0;
            bf16x4 o4;
            #pragma unroll
            for (int r = 0; r < 4; ++r) {
                float v = fmaxf(a[r] + ((const float*)&bv)[r], 0.f);
                s += v; q += v * v;
                o4[r] = (bf16_t)v;
            }
            const int bt = tbase + t2 * 16 + lm;
            *(bf16x4*)&xp1[(size_t)(b * 130 + 1 + bt) * 1024 + m0 + lh * 4] = o4;
        }
        s = wave_red_add(s); q = wave_red_add(q);
        if (l == 0) { bstat1[tile * 2] = s; bstat1[tile * 2 + 1] = q; }
    } else {
        // gemm: A = W^T rows (h), B = activation rows (bt/a), C[m=h][n=row].
        const bf16_t *At, *Bm;
        int h0, r0, is_tp;
        if (bid < 192) {
            const int unit = (bid - 128) * 4 + wv;       // 256 units: 8 bt x 32 h
            h0 = (unit & 31) * 32; r0 = (unit >> 5) * 32;
            At = w1topT; Bm = text_bf; is_tp = 1;
        } else {
            const int unit = (bid - 192) * 4 + wv;       // 1024 units: 32 a x 32 h
            h0 = (unit & 31) * 32; r0 = (unit >> 5) * 32;
            At = w1botT; Bm = audio_bf; is_tp = 0;
        }
        f32x4 acc[2][2];
        #pragma unroll
        for (int mt = 0; mt < 2; ++mt)
            #pragma unroll
            for (int nt = 0; nt < 2; ++nt) acc[mt][nt] = (f32x4)(0.0f);
        const bf16_t* Ap = At + (size_t)(h0 + lm) * 1024 + lk;
        const bf16_t* Bp = Bm + (size_t)(r0 + lm) * 1024 + lk;
#define G_A0(it) (*(const bf16x8*)(Ap + (it) * 32))
#define G_A1(it) (*(const bf16x8*)(Ap + 16384 + (it) * 32))
#define G_B0(it) (*(const bf16x8*)(Bp + (it) * 32))
#define G_B1(it) (*(const bf16x8*)(Bp + 16384 + (it) * 32))
        constexpr int PF = 4;
        bf16x8 qa0[PF], qa1[PF], qb0[PF], qb1[PF];
        #pragma unroll
        for (int it = 0; it < PF; ++it) {
            qa0[it] = G_A0(it); qa1[it] = G_A1(it);
            qb0[it] = G_B0(it); qb1[it] = G_B1(it);
        }
        #pragma unroll
        for (int it = 0; it < 32; ++it) {
            const int sl = it % PF;
            acc[0][0] = __builtin_amdgcn_mfma_f32_16x16x32_bf16(qa0[sl], qb0[sl], acc[0][0], 0, 0, 0);
            acc[0][1] = __builtin_amdgcn_mfma_f32_16x16x32_bf16(qa0[sl], qb1[sl], acc[0][1], 0, 0, 0);
            acc[1][0] = __builtin_amdgcn_mfma_f32_16x16x32_bf16(qa1[sl], qb0[sl], acc[1][0], 0, 0, 0);
            acc[1][1] = __builtin_amdgcn_mfma_f32_16x16x32_bf16(qa1[sl], qb1[sl], acc[1][1], 0, 0, 0);
            const int nx = it + PF;
            if (nx < 32) {
                qa0[sl] = G_A0(nx); qa1[sl] = G_A1(nx);
                qb0[sl] = G_B0(nx); qb1[sl] = G_B1(nx);
            }
        }
#undef G_A0
#undef G_A1
#undef G_B0
#undef G_B1
        if (is_tp) {
            #pragma unroll
            for (int mt = 0; mt < 2; ++mt) {
                const int hb = h0 + mt * 16 + lh * 4;
                float4 bv = *(const float4*)&a_b1[hb];
                #pragma unroll
                for (int nt = 0; nt < 2; ++nt) {
                    const int bt = r0 + nt * 16 + lm;
                    f16x4 v;
                    #pragma unroll
                    for (int r = 0; r < 4; ++r)
                        v[r] = (f16_t)(acc[mt][nt][r] + ((const float*)&bv)[r]);
                    *(f16x4*)&tp[(size_t)bt * 1024 + hb] = v;
                }
            }
        } else {
            #pragma unroll
            for (int mt = 0; mt < 2; ++mt) {
                const int hq = (h0 + mt * 16 + lh * 4) >> 2;
                #pragma unroll
                for (int nt = 0; nt < 2; ++nt) {
                    const int aa = r0 + nt * 16 + lm;
                    const int bb = aa >> 9, al = aa & 511;
                    f16x4 v;
                    #pragma unroll
                    for (int r = 0; r < 4; ++r) v[r] = (f16_t)acc[mt][nt][r];
                    *(f16x4*)&apT4[((size_t)hq * 1024 + bb * 512 + al) * 4] = v;
                }
            }
        }
    }
}

// ---------------------------------------------------------------------------
// P3: blocks [0,128) conv2 wave-tiles (GN1 folded, per-wave stat reduce);
//     blocks [128,640) logits (a split in halves of 256). No LDS.
// ---------------------------------------------------------------------------
__device__ __forceinline__ float dot2_acc(f16x2 x, f16x2 w, float acc) {
#if __has_builtin(__builtin_amdgcn_fdot2)
    return __builtin_amdgcn_fdot2(x, w, acc, false);
#else
    return acc + (float)x[0] * (float)w[0] + (float)x[1] * (float)w[1];
#endif
}

__global__ __launch_bounds__(256) void p3_k(
    const bf16_t* __restrict__ wc2, const bf16_t* __restrict__ xp1,
    const float* __restrict__ d_b2, bf16_t* __restrict__ y2,
    float* __restrict__ bstat2, const float* __restrict__ bstat1,
    const float* __restrict__ SgF, const float* __restrict__ SbF,
    const float* __restrict__ Sg3, const float* __restrict__ Sb3,
    const f16_t* __restrict__ tp, const f16_t* __restrict__ apT4,
    const f16_t* __restrict__ w2f, float* __restrict__ lp)
{
    const int bid = blockIdx.x;
    const int tid = threadIdx.x;
    if (bid < 128) {
        const int wv = tid >> 6, l = tid & 63;
        const int lm = l & 15, lh = l >> 4;
        const int tile = bid * 4 + wv;
        const int bx = tile >> 6, by = tile & 63;
        const int bt0 = bx * 32, m0 = by * 16;
        const int b = bt0 >> 7, tbase = bt0 & 127;
        f32x4 acc0 = (f32x4)(0.0f), acc1 = (f32x4)(0.0f);
        conv_mfma(wc2, xp1, m0, b, tbase, l, acc0, acc1);
        // per-wave GN1 stat reduce (256 (s,q) pairs = 128 float4)
        float s0, q0;
        {
            const float4* bp = (const float4*)bstat1 + (size_t)b * 128;
            float4 p0 = bp[l * 2], p1 = bp[l * 2 + 1];
            s0 = p0.x + p0.z + p1.x + p1.z;
            q0 = p0.y + p0.w + p1.y + p1.w;
        }
        s0 = wave_red_add(s0); q0 = wave_red_add(q0);
        const float mu = s0 * (1.f / 131072.f);
        const float rsig = rsqrtf(q0 * (1.f / 131072.f) - mu * mu + EPSV);
        float4 bv = *(const float4*)&d_b2[m0 + lh * 4];
        float4 gF = *(const float4*)&SgF[m0 + lh * 4];
        float4 bF = *(const float4*)&SbF[m0 + lh * 4];
        float s = 0.f, q = 0.f;
        #pragma unroll
        for (int t2 = 0; t2 < 2; ++t2) {
            f32x4 a = t2 ? acc1 : acc0;
            const int bt = tbase + t2 * 16 + lm;
            const bool e0 = (bt == 0), e1 = (bt == 127);
            bf16x4 o4;
            #pragma unroll
            for (int r = 0; r < 4; ++r) {
                const int o = m0 + lh * 4 + r;
                float sg = ((const float*)&gF)[r], sb = ((const float*)&bF)[r];
                if (e0) { sg -= Sg3[o * 3];     sb -= Sb3[o * 3]; }
                if (e1) { sg -= Sg3[o * 3 + 2]; sb -= Sb3[o * 3 + 2]; }
                float v = fmaxf(rsig * a[r] + sb - mu * rsig * sg + ((const float*)&bv)[r], 0.f);
                s += v; q += v * v;
                o4[r] = (bf16_t)v;
            }
            *(bf16x4*)&y2[(size_t)(b * 128 + bt) * 1024 + m0 + lh * 4] = o4;
        }
        s = wave_red_add(s); q = wave_red_add(q);
        if (l == 0) { bstat2[tile * 2] = s; bstat2[tile * 2 + 1] = q; }
    } else {
        const int lb = bid - 128;                       // 512 blocks
        const int hc = lb >> 7, btp = (lb >> 1) & 63, half = lb & 1;
        const int bt0 = btp * 4;
        const int b = bt0 >> 7;
        const int a = half * 256 + tid;
        const f16_t* tpr = tp + (size_t)bt0 * 1024 + hc * 256;   // wave-uniform
        const f16_t* w2r = w2f + hc * 256;
        const f16_t* apc = apT4 + ((size_t)(hc * 64) * 1024 + b * 512 + a) * 4;
        float acc[4] = {0.f, 0.f, 0.f, 0.f};
        const f16x2 zero = (f16x2)(f16_t)0.0f;
#define L_A0(i) (*(const f16x4*)(apc + (size_t)(2 * (i)) * 4096))
#define L_A1(i) (*(const f16x4*)(apc + (size_t)(2 * (i) + 1) * 4096))
        constexpr int PF = 4;
        f16x4 pa[PF], pb[PF];
        #pragma unroll
        for (int i = 0; i < PF; ++i) { pa[i] = L_A0(i); pb[i] = L_A1(i); }
        #pragma unroll
        for (int i = 0; i < 32; ++i) {                  // hq pair per iter
            const int sl = i % PF;
            const int hq = 2 * i;
            f16x4 a0 = pa[sl], a1 = pb[sl];
            f16x4 w0 = *(const f16x4*)&w2r[hq * 4];
            f16x4 w1 = *(const f16x4*)&w2r[hq * 4 + 4];
            #pragma unroll
            for (int r = 0; r < 4; ++r) {
                f16x4 t0 = *(const f16x4*)&tpr[r * 1024 + hq * 4];
                f16x4 t1 = *(const f16x4*)&tpr[r * 1024 + hq * 4 + 4];
                f16x2 p;
                p = __builtin_elementwise_max((f16x2){t0[0] + a0[0], t0[1] + a0[1]}, zero);
                acc[r] = dot2_acc(p, (f16x2){w0[0], w0[1]}, acc[r]);
                p = __builtin_elementwise_max((f16x2){t0[2] + a0[2], t0[3] + a0[3]}, zero);
                acc[r] = dot2_acc(p, (f16x2){w0[2], w0[3]}, acc[r]);
                p = __builtin_elementwise_max((f16x2){t1[0] + a1[0], t1[1] + a1[1]}, zero);
                acc[r] = dot2_acc(p, (f16x2){w1[0], w1[1]}, acc[r]);
                p = __builtin_elementwise_max((f16x2){t1[2] + a1[2], t1[3] + a1[3]}, zero);
                acc[r] = dot2_acc(p, (f16x2){w1[2], w1[3]}, acc[r]);
            }
            const int nx = i + PF;
            if (nx < 32) { pa[sl] = L_A0(nx); pb[sl] = L_A1(nx); }
        }
#undef L_A0
#undef L_A1
        float* dst = lp + (size_t)(hc * 256 + bt0) * 512 + a;
        #pragma unroll
        for (int r = 0; r < 4; ++r) dst[(size_t)r * 512] = acc[r];
    }
}

// reduce 256 (s,q) pairs for batch b from bstat (block-level, 512 threads).
__device__ __forceinline__ void reduce_bstat(
    const float* __restrict__ bstat, int b, int tid,
    float* sr, float* sq, float& mu, float& rsig)
{
    const int lane = tid & 63, wid = tid >> 6;
    float s = 0.f, q = 0.f;
    if (tid < 256) {
        float2 v = ((const float2*)bstat)[b * 256 + tid];
        s = v.x; q = v.y;
    }
    #pragma unroll
    for (int off = 32; off > 0; off >>= 1) {
        s += __shfl_xor(s, off);
        q += __shfl_xor(q, off);
    }
    if (lane == 0) { sr[wid] = s; sq[wid] = q; }
    __syncthreads();
    float ts = 0.f, tq = 0.f;
    #pragma unroll
    for (int i = 0; i < 8; ++i) { ts += sr[i]; tq += sq[i]; }
    const float cnt = 131072.f;
    mu = ts / cnt;
    const float var = tq / cnt - mu * mu;
    rsig = rsqrtf(var + EPSV);
}

// ---------------------------------------------------------------------------
// combine: blocks [0,256): sum lp chunks + bias + monotonic, softmax -> out.
//          blocks [256,288): conv3 + GN2 (reduced from bstat2) + softplus.
// ---------------------------------------------------------------------------
__global__ __launch_bounds__(512) void combine_k(
    const float* __restrict__ lp, const float* __restrict__ b2,
    const bf16_t* __restrict__ y2, const float* __restrict__ bstat2,
    const float* __restrict__ g, const float* __restrict__ bet,
    const float* __restrict__ w3, const float* __restrict__ b3,
    float* __restrict__ out)
{
    __shared__ float redm[8], redsum[8];
    const int bid = blockIdx.x;
    const int tid = threadIdx.x;
    if (bid < 256) {
        const int bt = bid, t = bt & 127;
        const int a = tid;
        const int lane = a & 63, wid = a >> 6;
        const size_t base = (size_t)bt * 512 + a;
        float v = lp[base] + lp[131072 + base] + lp[262144 + base] + lp[393216 + base];
        v += b2[0] - 0.1f * fabsf((float)a - 4.0f * (float)t);
        float m = v;
        #pragma unroll
        for (int off = 32; off > 0; off >>= 1) m = fmaxf(m, __shfl_xor(m, off));
        if (lane == 0) redm[wid] = m;
        __syncthreads();
        float M = redm[0];
        #pragma unroll
        for (int i = 1; i < 8; ++i) M = fmaxf(M, redm[i]);
        const float e = expf(v - M);
        float s = e;
        #pragma unroll
        for (int off = 32; off > 0; off >>= 1) s += __shfl_xor(s, off);
        if (lane == 0) redsum[wid] = s;
        __syncthreads();
        float S = redsum[0];
        #pragma unroll
        for (int i = 1; i < 8; ++i) S += redsum[i];
        out[(size_t)bt * 512 + a] = e * (1.0f / S);
    } else {
        // conv3 + GN2-fold + softplus; mu/var reduced from conv2 partials.
        const int cb = bid - 256;              // 0..31, bt [cb*8, cb*8+8)
        const int b = (cb * 8) >> 7;
        float mu, rsig;
        reduce_bstat(bstat2, b, tid, redm, redsum, mu, rsig);
        const int lane = tid & 63, w = tid >> 6;
        const int bt = cb * 8 + w;
        const bf16_t* row = y2 + (size_t)bt * 1024 + lane * 16;
        float s1 = 0.f, s2 = 0.f, s3 = 0.f;
        #pragma unroll
        for (int c = 0; c < 2; ++c) {
            bf16x8 yv = *(const bf16x8*)(row + c * 8);
            #pragma unroll
            for (int j = 0; j < 8; ++j) {
                const int i = lane * 16 + c * 8 + j;
                const float gw = g[i] * w3[i];
                s1 += gw * (float)yv[j];
                s2 += gw;
                s3 += bet[i] * w3[i];
            }
        }
        #pragma unroll
        for (int off = 32; off > 0; off >>= 1) {
            s1 += __shfl_xor(s1, off);
            s2 += __shfl_xor(s2, off);
            s3 += __shfl_xor(s3, off);
        }
        if (lane == 0) {
            const float t = rsig * (s1 - mu * s2) + s3 + b3[0];
            out[131072 + bt] = fmaxf(t, 0.f) + log1pf(expf(-fabsf(t)));
        }
    }
}

extern "C" void kernel_launch(void* const* d_in, const int* in_sizes, int n_in,
                              void* d_out, int out_size, void* d_ws, size_t ws_size,
                              hipStream_t stream) {
    const float* text   = (const float*)d_in[0];
    const float* audio  = (const float*)d_in[1];
    const float* a_w1   = (const float*)d_in[2];
    const float* a_b1   = (const float*)d_in[3];
    const float* a_w2   = (const float*)d_in[4];
    const float* a_b2   = (const float*)d_in[5];
    const float* d_w1   = (const float*)d_in[6];
    const float* d_b1   = (const float*)d_in[7];
    const float* gn1_g  = (const float*)d_in[8];
    const float* gn1_b  = (const float*)d_in[9];
    const float* d_w2   = (const float*)d_in[10];
    const float* d_b2   = (const float*)d_in[11];
    const float* gn2_g  = (const float*)d_in[12];
    const float* gn2_b  = (const float*)d_in[13];
    const float* d_w3   = (const float*)d_in[14];
    const float* d_b3   = (const float*)d_in[15];

    char* ws = (char*)d_ws;
    float* outf = (float*)d_out;

    bf16_t* text_bf  = (bf16_t*)(ws + OFF_TEXTBF);
    bf16_t* audio_bf = (bf16_t*)(ws + OFF_AUDIOBF);
    bf16_t* w1topT   = (bf16_t*)(ws + OFF_W1TOP);
    bf16_t* w1botT   = (bf16_t*)(ws + OFF_W1BOT);
    bf16_t* wc1      = (bf16_t*)(ws + OFF_WC1);
    bf16_t* wc2      = (bf16_t*)(ws + OFF_WC2);
    f16_t*  tp       = (f16_t*) (ws + OFF_TP);
    f16_t*  w2f      = (f16_t*) (ws + OFF_W2F);
    f16_t*  apT4     = (f16_t*) (ws + OFF_APT);
    bf16_t* xp0      = (bf16_t*)(ws + OFF_XP0);
    bf16_t* xp1      = (bf16_t*)(ws + OFF_XP1);
    bf16_t* y2       = (bf16_t*)(ws + OFF_Y2);
    float*  bstat1   = (float*) (ws + OFF_BST1);
    float*  bstat2   = (float*) (ws + OFF_BST2);
    float*  lp       = (float*) (ws + OFF_LP);
    float*  Sg3     = (float*) (ws + OFF_SG);
    float*  Sb3     = (float*) (ws + OFF_SB);
    float*  SgFp    = (float*) (ws + OFF_SGF);
    float*  SbFp    = (float*) (ws + OFF_SBF);

    // 1: prep (cvt activations, w1 transpose, conv weights + sums, pads, w2f)
    prep_k<<<dim3(5377), 256, 0, stream>>>(text, audio, a_w1, d_w1, d_w2, a_w2,
                                           gn1_g, gn1_b,
                                           text_bf, xp0, audio_bf, w1topT, w1botT,
                                           wc1, wc2, xp1, w2f, Sg3, Sb3,
                                           SgFp, SbFp);
    // 2: conv1 wave-tiles ∥ tp gemm ∥ ap gemm (448 blocks x 256 thr, no LDS)
    p2_k<<<dim3(448), 256, 0, stream>>>(wc1, xp0, d_b1, xp1, bstat1,
                                        text_bf, w1topT, a_b1, tp,
                                        audio_bf, w1botT, apT4);
    // 3: conv2 (GN1 folded) ∥ logits partials (640 blocks x 256 thr)
    p3_k<<<dim3(640), 256, 0, stream>>>(wc2, xp1, d_b2, y2, bstat2, bstat1,
                                        SgFp, SbFp, Sg3, Sb3, tp, apT4, w2f, lp);
    // 4: combine+softmax -> alignment; conv3+GN2(reduced)+softplus -> durations
    combine_k<<<dim3(288), 512, 0, stream>>>(lp, a_b2, y2, bstat2,
                                             gn2_g, gn2_b, d_w3, d_b3, outf);
}

// Round 4
// 179.522 us; speedup vs baseline: 1.1554x; 1.1475x over previous
//
#include <hip/hip_runtime.h>
#include <hip/hip_bf16.h>

// ---------------------------------------------------------------------------
// MonotonicAlignmentSearch R16: straight-line load-then-consume waves.
// R15's rotating register queue was collapsed by the compiler (VGPR 48,
// MfmaUtil 3%). Now: 8-wave blocks, K split across waves, each wave issues
// ALL its K-slice loads as independent back-to-back loads (18 or 16 in
// flight), then consumes via MFMA in issue order (vmcnt retires in order).
// Partials reduced via padded LDS. conv: 16x32 tile/block, wave K=384 (2
// segments of 18 loads). gemm: 32x32 tile/block, wave K=128 (16 loads).
// B=2, TT=128, TA=512, H=1024.
// ---------------------------------------------------------------------------

typedef __bf16 bf16_t;
typedef __bf16 bf16x8 __attribute__((ext_vector_type(8)));
typedef __bf16 bf16x4 __attribute__((ext_vector_type(4)));
typedef float  f32x4  __attribute__((ext_vector_type(4)));
typedef _Float16 f16_t;
typedef _Float16 f16x2 __attribute__((ext_vector_type(2)));
typedef _Float16 f16x4 __attribute__((ext_vector_type(4)));

#define EPSV 1e-5f

// ---- workspace offsets (bytes) — no overlays, ~26.3 MB << 256 MB ws -------
#define OFF_TEXTBF   0u          //  524288  bf16 text [256][1024]
#define OFF_AUDIOBF  524288u     // 2097152  bf16 audio [1024][1024]
#define OFF_W1TOP    2621440u    // 2097152  bf16 W1topT [1024 d][1024 h]
#define OFF_W1BOT    4718592u    // 2097152  bf16 W1botT [1024 d][1024 h]
#define OFF_WC1      6815744u    // 6291456  bf16 Wc1 [3][1024][1024]
#define OFF_WC2      13107200u   // 6291456  bf16 Wc2 [3][1024][1024] (g-scaled)
#define OFF_TP       19398656u   //  524288  f16 tp [256 bt][1024 d] (bias folded)
#define OFF_W2F      19922944u   //    2048  f16 w2 [1024]
#define OFF_APT      20447232u   // 2097152  f16 apT4 [256 hq][1024 ba][4]
#define OFF_XP0      22544384u   //  532480  bf16 xp0 [2][130][1024]
#define OFF_XP1      23076864u   //  532480  bf16 xp1 [2][130][1024] (raw relu)
#define OFF_Y2       23609344u   //  524288  bf16 y2 [256][1024] (pre-GN2)
#define OFF_BST1     24133632u   //    4096  f32 bstat1 [512][2] (conv1 partials)
#define OFF_BST2     24137728u   //    4096  f32 bstat2 [512][2] (conv2 partials)
#define OFF_LP       24141824u   // 2097152  f32 lp [4 hc][256 bt][512 a]
#define OFF_SG       26238976u   //   12288  f32 Sg [1024][3]  (sum_c w2*g)
#define OFF_SB       26251264u   //   12288  f32 Sb [1024][3]  (sum_c w2*beta)
#define OFF_SGF      26263552u   //    4096  f32 SgF [1024] (full tap sum)
#define OFF_SBF      26267648u   //    4096  f32 SbF [1024]

// ---------------------------------------------------------------------------
// prep: [0,1280) cvt activations; [1280,3328) w1 transpose-cast;
// [3328,5376) conv-weight cvt (wc2 g-scaled + Sg/Sb/SgF/SbF sums);
// 5376: zero pads + w2->f16.
// ---------------------------------------------------------------------------
__global__ __launch_bounds__(256) void prep_k(
    const float* __restrict__ text, const float* __restrict__ audio,
    const float* __restrict__ w1,
    const float* __restrict__ w1c, const float* __restrict__ w2c,
    const float* __restrict__ w2,
    const float* __restrict__ g1, const float* __restrict__ b1g,
    bf16_t* __restrict__ text_bf, bf16_t* __restrict__ xp0,
    bf16_t* __restrict__ audio_bf,
    bf16_t* __restrict__ topT, bf16_t* __restrict__ botT,
    bf16_t* __restrict__ wc1, bf16_t* __restrict__ wc2,
    bf16_t* __restrict__ xp1, f16_t* __restrict__ w2f,
    float* __restrict__ Sg, float* __restrict__ Sb,
    float* __restrict__ SgF, float* __restrict__ SbF)
{
    __shared__ float tile[32][33];
    const int bid = blockIdx.x;
    if (bid < 1280) {
        const int e = (bid * 256 + threadIdx.x) * 4;   // 1310720 total
        if (e < 262144) {
            float4 v = *(const float4*)&text[e];
            bf16x4 o; o[0] = (bf16_t)v.x; o[1] = (bf16_t)v.y; o[2] = (bf16_t)v.z; o[3] = (bf16_t)v.w;
            *(bf16x4*)&text_bf[e] = o;
            const int bt = e >> 10, h = e & 1023;
            const int b = bt >> 7, t = bt & 127;
            *(bf16x4*)&xp0[(size_t)(b * 130 + 1 + t) * 1024 + h] = o;
        } else {
            const int ea = e - 262144;
            float4 v = *(const float4*)&audio[ea];
            bf16x4 o; o[0] = (bf16_t)v.x; o[1] = (bf16_t)v.y; o[2] = (bf16_t)v.z; o[3] = (bf16_t)v.w;
            *(bf16x4*)&audio_bf[ea] = o;
        }
    } else if (bid < 3328) {
        const int b2 = bid - 1280;
        const int bx = b2 & 31, by = b2 >> 5;          // (32, 64)
        const int tx = threadIdx.x & 31, ty = threadIdx.x >> 5;
        #pragma unroll
        for (int j = 0; j < 4; ++j)
            tile[ty + j * 8][tx] = w1[(size_t)(by * 32 + ty + j * 8) * 1024 + bx * 32 + tx];
        __syncthreads();
        bf16_t* out = (by < 32) ? topT : botT;
        const int hbase = (by & 31) * 32;
        #pragma unroll
        for (int j = 0; j < 4; ++j) {
            const int d = bx * 32 + ty + j * 8;
            out[(size_t)d * 1024 + hbase + tx] = (bf16_t)tile[tx][ty + j * 8];
        }
    } else if (bid < 5376) {
        int b2 = bid - 3328;
        const int is2 = (b2 >= 1024) ? 1 : 0;
        const float* w = is2 ? w2c : w1c;
        bf16_t* wc = is2 ? wc2 : wc1;
        b2 &= 1023;
        const int o = b2, i4 = threadIdx.x;            // one block per out-chan
        const float* src = w + (size_t)o * 3072 + i4 * 12;
        float4 v0 = *(const float4*)&src[0];
        float4 v1 = *(const float4*)&src[4];
        float4 v2 = *(const float4*)&src[8];
        const float f[12] = {v0.x, v0.y, v0.z, v0.w, v1.x, v1.y, v1.z, v1.w, v2.x, v2.y, v2.z, v2.w};
        float g4[4] = {1.f, 1.f, 1.f, 1.f}, bb4[4] = {0.f, 0.f, 0.f, 0.f};
        if (is2) {
            float4 gv = *(const float4*)&g1[i4 * 4];
            float4 bv = *(const float4*)&b1g[i4 * 4];
            g4[0] = gv.x; g4[1] = gv.y; g4[2] = gv.z; g4[3] = gv.w;
            bb4[0] = bv.x; bb4[1] = bv.y; bb4[2] = bv.z; bb4[3] = bv.w;
        }
        float sgr[3] = {0.f, 0.f, 0.f}, sbr[3] = {0.f, 0.f, 0.f};
        #pragma unroll
        for (int r = 0; r < 3; ++r) {
            bf16x4 o4;
            #pragma unroll
            for (int j = 0; j < 4; ++j) {
                const float wv = f[j * 3 + r];
                const float ws = wv * g4[j];
                sgr[r] += ws;
                sbr[r] += wv * bb4[j];
                o4[j] = (bf16_t)(is2 ? ws : wv);
            }
            *(bf16x4*)&wc[(size_t)r * 1048576 + (size_t)o * 1024 + i4 * 4] = o4;
        }
        if (is2) {
            #pragma unroll
            for (int off = 32; off > 0; off >>= 1) {
                #pragma unroll
                for (int r = 0; r < 3; ++r) {
                    sgr[r] += __shfl_xor(sgr[r], off);
                    sbr[r] += __shfl_xor(sbr[r], off);
                }
            }
            float* red = &tile[0][0];
            const int wid = threadIdx.x >> 6, lane = threadIdx.x & 63;
            if (lane == 0) {
                #pragma unroll
                for (int r = 0; r < 3; ++r) {
                    red[wid * 6 + r] = sgr[r];
                    red[wid * 6 + 3 + r] = sbr[r];
                }
            }
            __syncthreads();
            if (threadIdx.x < 6) {
                const float v = red[threadIdx.x] + red[6 + threadIdx.x]
                              + red[12 + threadIdx.x] + red[18 + threadIdx.x];
                if (threadIdx.x < 3) Sg[o * 3 + threadIdx.x] = v;
                else                 Sb[o * 3 + threadIdx.x - 3] = v;
                red[24 + threadIdx.x] = v;
            }
            __syncthreads();
            if (threadIdx.x == 0)      SgF[o] = red[24] + red[25] + red[26];
            else if (threadIdx.x == 1) SbF[o] = red[27] + red[28] + red[29];
        }
    } else {
        const int tid = threadIdx.x;
        const int rowmap[4] = {0, 129, 130, 259};
        const int f = tid * 16;
        const int r = f >> 10, w = f & 1023;
        bf16x8 z8 = (bf16x8)(bf16_t)0.0f;
        bf16_t* p0 = xp0 + (size_t)rowmap[r] * 1024 + w;
        bf16_t* p1 = xp1 + (size_t)rowmap[r] * 1024 + w;
        *(bf16x8*)p0 = z8; *(bf16x8*)(p0 + 8) = z8;
        *(bf16x8*)p1 = z8; *(bf16x8*)(p1 + 8) = z8;
        float4 wv = *(const float4*)&w2[tid * 4];
        f16x4 wo; wo[0] = (f16_t)wv.x; wo[1] = (f16_t)wv.y; wo[2] = (f16_t)wv.z; wo[3] = (f16_t)wv.w;
        *(f16x4*)&w2f[tid * 4] = wo;
    }
}

// ---------------------------------------------------------------------------
// helpers
// ---------------------------------------------------------------------------
__device__ __forceinline__ float wave_red_add(float v) {
    #pragma unroll
    for (int off = 32; off > 0; off >>= 1) v += __shfl_xor(v, off);
    return v;
}

// Per-wave conv K-slice: wave w handles k in [w*128, w*128+128) of each tap.
// 12 chunks total, loaded as 2 straight-line segments of 18 independent
// loads, consumed in issue order. acc0 = bt cols tbase..+15, acc1 = +16..31.
__device__ __forceinline__ void conv_wave_partial(
    const bf16_t* __restrict__ Wc, const bf16_t* __restrict__ xp,
    int m0, int b, int tbase, int w, int l, f32x4& acc0, f32x4& acc1)
{
    const int lm = l & 15, lk = (l >> 4) * 8;
    const int koff = w * 128;
    const bf16_t* aq = Wc + (size_t)(m0 + lm) * 1024 + koff + lk;
    const bf16_t* bq = xp + (size_t)(b * 130 + tbase + lm) * 1024 + koff + lk;
    #pragma unroll
    for (int s = 0; s < 2; ++s) {
        bf16x8 ra[6], rb0[6], rb1[6];
        #pragma unroll
        for (int j = 0; j < 6; ++j) {
            const int idx = s * 6 + j;            // 0..11
            const int rr = idx >> 2, cc = idx & 3;
            const bf16_t* pa = aq + (size_t)rr * 1048576 + cc * 32;
            const bf16_t* pb = bq + (size_t)rr * 1024 + cc * 32;
            ra[j]  = *(const bf16x8*)pa;
            rb0[j] = *(const bf16x8*)pb;
            rb1[j] = *(const bf16x8*)(pb + 16384);
        }
        #pragma unroll
        for (int j = 0; j < 6; ++j) {
            acc0 = __builtin_amdgcn_mfma_f32_16x16x32_bf16(ra[j], rb0[j], acc0, 0, 0, 0);
            acc1 = __builtin_amdgcn_mfma_f32_16x16x32_bf16(ra[j], rb1[j], acc1, 0, 0, 0);
        }
    }
}

// ---------------------------------------------------------------------------
// P2: blocks [0,512) conv1 tiles (16ch x 32bt, 8-way K-split, LDS reduce);
//     [512,768) tp gemm; [768,1792) ap gemm (32x32, 8-way K-split).
// ---------------------------------------------------------------------------
__global__ __launch_bounds__(512) void p2_k(
    const bf16_t* __restrict__ wc1, const bf16_t* __restrict__ xp0,
    const float* __restrict__ d_b1, bf16_t* __restrict__ xp1,
    float* __restrict__ bstat1,
    const bf16_t* __restrict__ text_bf, const bf16_t* __restrict__ w1topT,
    const float* __restrict__ a_b1, f16_t* __restrict__ tp,
    const bf16_t* __restrict__ audio_bf, const bf16_t* __restrict__ w1botT,
    f16_t* __restrict__ apT4)
{
    __shared__ float smem[8448];                 // gemm: [8][32][33]; conv: [8][16][33]
    __shared__ float sred[8], sredq[8];
    const int bid = blockIdx.x;
    const int tid = threadIdx.x;
    const int w = tid >> 6, l = tid & 63;
    const int lm = l & 15, lh = l >> 4, lk = lh * 8;
    if (bid < 512) {
        // ---- conv1 tile: bx = bid>>6 (bt group), by = bid&63 (chan group) --
        const int bx = bid >> 6, by = bid & 63;
        const int bt0 = bx * 32, m0 = by * 16;
        const int b = bt0 >> 7, tbase = bt0 & 127;
        f32x4 acc0 = (f32x4)(0.0f), acc1 = (f32x4)(0.0f);
        conv_wave_partial(wc1, xp0, m0, b, tbase, w, l, acc0, acc1);
        float* sl = smem + w * 528;
        #pragma unroll
        for (int r = 0; r < 4; ++r) {
            sl[(lh * 4 + r) * 33 + lm] = acc0[r];
            sl[(lh * 4 + r) * 33 + 16 + lm] = acc1[r];
        }
        __syncthreads();
        const int mm = tid >> 5, nn = tid & 31;  // chan-local, bt-local
        float v = 0.f;
        #pragma unroll
        for (int ww = 0; ww < 8; ++ww) v += smem[ww * 528 + mm * 33 + nn];
        v = fmaxf(v + d_b1[m0 + mm], 0.f);
        float s = wave_red_add(v), q = wave_red_add(v * v);
        if (l == 0) { sred[w] = s; sredq[w] = q; }
        xp1[(size_t)(b * 130 + 1 + tbase + nn) * 1024 + m0 + mm] = (bf16_t)v;
        __syncthreads();
        if (tid == 0) {
            float ts = 0.f, tq = 0.f;
            #pragma unroll
            for (int ww = 0; ww < 8; ++ww) { ts += sred[ww]; tq += sredq[ww]; }
            bstat1[bid * 2] = ts; bstat1[bid * 2 + 1] = tq;
        }
    } else {
        // ---- gemm 32x32 tile, 8-way K-split (wave w: k in [w*128,+128)) ---
        const bf16_t *At, *Bm;
        int d0, r0, is_tp;
        if (bid < 768) {
            const int unit = bid - 512;          // 256 units: 8 bt x 32 d
            d0 = (unit & 31) * 32; r0 = (unit >> 5) * 32;
            At = w1topT; Bm = text_bf; is_tp = 1;
        } else {
            const int unit = bid - 768;          // 1024 units: 32 a x 32 d
            d0 = (unit & 31) * 32; r0 = (unit >> 5) * 32;
            At = w1botT; Bm = audio_bf; is_tp = 0;
        }
        const int koff = w * 128;
        const bf16_t* Ap = At + (size_t)(d0 + lm) * 1024 + koff + lk;
        const bf16_t* Bp = Bm + (size_t)(r0 + lm) * 1024 + koff + lk;
        bf16x8 qa0[4], qa1[4], qb0[4], qb1[4];
        #pragma unroll
        for (int cc = 0; cc < 4; ++cc) {
            qa0[cc] = *(const bf16x8*)(Ap + cc * 32);
            qa1[cc] = *(const bf16x8*)(Ap + 16384 + cc * 32);
            qb0[cc] = *(const bf16x8*)(Bp + cc * 32);
            qb1[cc] = *(const bf16x8*)(Bp + 16384 + cc * 32);
        }
        f32x4 acc[2][2];
        #pragma unroll
        for (int mt = 0; mt < 2; ++mt)
            #pragma unroll
            for (int nt = 0; nt < 2; ++nt) acc[mt][nt] = (f32x4)(0.0f);
        #pragma unroll
        for (int cc = 0; cc < 4; ++cc) {
            acc[0][0] = __builtin_amdgcn_mfma_f32_16x16x32_bf16(qa0[cc], qb0[cc], acc[0][0], 0, 0, 0);
            acc[0][1] = __builtin_amdgcn_mfma_f32_16x16x32_bf16(qa0[cc], qb1[cc], acc[0][1], 0, 0, 0);
            acc[1][0] = __builtin_amdgcn_mfma_f32_16x16x32_bf16(qa1[cc], qb0[cc], acc[1][0], 0, 0, 0);
            acc[1][1] = __builtin_amdgcn_mfma_f32_16x16x32_bf16(qa1[cc], qb1[cc], acc[1][1], 0, 0, 0);
        }
        float* sl = smem + w * 1056;
        #pragma unroll
        for (int mt = 0; mt < 2; ++mt)
            #pragma unroll
            for (int nt = 0; nt < 2; ++nt)
                #pragma unroll
                for (int r = 0; r < 4; ++r)
                    sl[(mt * 16 + lh * 4 + r) * 33 + nt * 16 + lm] = acc[mt][nt][r];
        __syncthreads();
        const int m = tid >> 4, n2 = (tid & 15) * 2;     // d-local, row-local pair
        float v0 = 0.f, v1 = 0.f;
        #pragma unroll
        for (int ww = 0; ww < 8; ++ww) {
            v0 += smem[ww * 1056 + m * 33 + n2];
            v1 += smem[ww * 1056 + m * 33 + n2 + 1];
        }
        if (is_tp) {
            const float bb = a_b1[d0 + m];
            tp[(size_t)(r0 + n2) * 1024 + d0 + m] = (f16_t)(v0 + bb);
            tp[(size_t)(r0 + n2 + 1) * 1024 + d0 + m] = (f16_t)(v1 + bb);
        } else {
            const int h = d0 + m, hq = h >> 2, hr = h & 3;
            const int a0 = r0 + n2;
            const int bbk = a0 >> 9, al = a0 & 511;
            apT4[((size_t)hq * 1024 + bbk * 512 + al) * 4 + hr] = (f16_t)v0;
            apT4[((size_t)hq * 1024 + bbk * 512 + al + 1) * 4 + hr] = (f16_t)v1;
        }
    }
}

// reduce 256 (s,q) pairs for batch b from bstat (block-level, 512 threads).
__device__ __forceinline__ void reduce_bstat(
    const float* __restrict__ bstat, int b, int tid,
    float* sr, float* sq, float& mu, float& rsig)
{
    const int lane = tid & 63, wid = tid >> 6;
    float s = 0.f, q = 0.f;
    if (tid < 256) {
        float2 v = ((const float2*)bstat)[b * 256 + tid];
        s = v.x; q = v.y;
    }
    #pragma unroll
    for (int off = 32; off > 0; off >>= 1) {
        s += __shfl_xor(s, off);
        q += __shfl_xor(q, off);
    }
    if (lane == 0) { sr[wid] = s; sq[wid] = q; }
    __syncthreads();
    float ts = 0.f, tq = 0.f;
    #pragma unroll
    for (int i = 0; i < 8; ++i) { ts += sr[i]; tq += sq[i]; }
    const float cnt = 131072.f;
    mu = ts / cnt;
    const float var = tq / cnt - mu * mu;
    rsig = rsqrtf(var + EPSV);
}

// ---------------------------------------------------------------------------
// P3: blocks [0,512) conv2 tiles (GN1 folded analytically);
//     [512,768) logits blocks (512 threads = full a-range).
// ---------------------------------------------------------------------------
__device__ __forceinline__ float dot2_acc(f16x2 x, f16x2 w, float acc) {
#if __has_builtin(__builtin_amdgcn_fdot2)
    return __builtin_amdgcn_fdot2(x, w, acc, false);
#else
    return acc + (float)x[0] * (float)w[0] + (float)x[1] * (float)w[1];
#endif
}

__global__ __launch_bounds__(512) void p3_k(
    const bf16_t* __restrict__ wc2, const bf16_t* __restrict__ xp1,
    const float* __restrict__ d_b2, bf16_t* __restrict__ y2,
    float* __restrict__ bstat2, const float* __restrict__ bstat1,
    const float* __restrict__ SgF, const float* __restrict__ SbF,
    const float* __restrict__ Sg3, const float* __restrict__ Sb3,
    const f16_t* __restrict__ tp, const f16_t* __restrict__ apT4,
    const f16_t* __restrict__ w2f, float* __restrict__ lp)
{
    __shared__ float smem[4224];                 // conv: [8][16][33]
    __shared__ float sred[8], sredq[8], sr[8], sq[8];
    const int bid = blockIdx.x;
    const int tid = threadIdx.x;
    if (bid < 512) {
        const int w = tid >> 6, l = tid & 63;
        const int lm = l & 15, lh = l >> 4;
        const int bx = bid >> 6, by = bid & 63;
        const int bt0 = bx * 32, m0 = by * 16;
        const int b = bt0 >> 7, tbase = bt0 & 127;
        f32x4 acc0 = (f32x4)(0.0f), acc1 = (f32x4)(0.0f);
        conv_wave_partial(wc2, xp1, m0, b, tbase, w, l, acc0, acc1);
        float* sl = smem + w * 528;
        #pragma unroll
        for (int r = 0; r < 4; ++r) {
            sl[(lh * 4 + r) * 33 + lm] = acc0[r];
            sl[(lh * 4 + r) * 33 + 16 + lm] = acc1[r];
        }
        __syncthreads();
        const int mm = tid >> 5, nn = tid & 31;
        float vraw = 0.f;
        #pragma unroll
        for (int ww = 0; ww < 8; ++ww) vraw += smem[ww * 528 + mm * 33 + nn];
        float mu, rsig;
        reduce_bstat(bstat1, b, tid, sr, sq, mu, rsig);   // has its own barrier
        const int o = m0 + mm, tloc = tbase + nn;
        float sg = SgF[o], sb = SbF[o];
        if (tloc == 0)   { sg -= Sg3[o * 3];     sb -= Sb3[o * 3]; }
        if (tloc == 127) { sg -= Sg3[o * 3 + 2]; sb -= Sb3[o * 3 + 2]; }
        float v = fmaxf(rsig * vraw + sb - mu * rsig * sg + d_b2[o], 0.f);
        float s = wave_red_add(v), q = wave_red_add(v * v);
        if ((tid & 63) == 0) { sred[tid >> 6] = s; sredq[tid >> 6] = q; }
        y2[(size_t)(b * 128 + tloc) * 1024 + o] = (bf16_t)v;
        __syncthreads();
        if (tid == 0) {
            float ts = 0.f, tq = 0.f;
            #pragma unroll
            for (int ww = 0; ww < 8; ++ww) { ts += sred[ww]; tq += sredq[ww]; }
            bstat2[bid * 2] = ts; bstat2[bid * 2 + 1] = tq;
        }
    } else {
        const int lb = bid - 512;                       // 256 blocks
        const int hc = lb >> 6, btp = lb & 63;
        const int bt0 = btp * 4;
        const int b = bt0 >> 7;
        const int a = tid;                              // 0..511
        const f16_t* tpr = tp + (size_t)bt0 * 1024 + hc * 256;   // wave-uniform
        const f16_t* w2r = w2f + hc * 256;
        const f16_t* apc = apT4 + ((size_t)(hc * 64) * 1024 + b * 512 + a) * 4;
        float acc[4] = {0.f, 0.f, 0.f, 0.f};
        const f16x2 zero = (f16x2)(f16_t)0.0f;
#define L_A0(i) (*(const f16x4*)(apc + (size_t)(2 * (i)) * 4096))
#define L_A1(i) (*(const f16x4*)(apc + (size_t)(2 * (i) + 1) * 4096))
        constexpr int PF = 4;
        f16x4 pa[PF], pb[PF];
        #pragma unroll
        for (int i = 0; i < PF; ++i) { pa[i] = L_A0(i); pb[i] = L_A1(i); }
        #pragma unroll
        for (int i = 0; i < 32; ++i) {                  // hq pair per iter
            const int sl = i % PF;
            const int hq = 2 * i;
            f16x4 a0 = pa[sl], a1 = pb[sl];
            f16x4 w0 = *(const f16x4*)&w2r[hq * 4];
            f16x4 w1 = *(const f16x4*)&w2r[hq * 4 + 4];
            #pragma unroll
            for (int r = 0; r < 4; ++r) {
                f16x4 t0 = *(const f16x4*)&tpr[r * 1024 + hq * 4];
                f16x4 t1 = *(const f16x4*)&tpr[r * 1024 + hq * 4 + 4];
                f16x2 p;
                p = __builtin_elementwise_max((f16x2){t0[0] + a0[0], t0[1] + a0[1]}, zero);
                acc[r] = dot2_acc(p, (f16x2){w0[0], w0[1]}, acc[r]);
                p = __builtin_elementwise_max((f16x2){t0[2] + a0[2], t0[3] + a0[3]}, zero);
                acc[r] = dot2_acc(p, (f16x2){w0[2], w0[3]}, acc[r]);
                p = __builtin_elementwise_max((f16x2){t1[0] + a1[0], t1[1] + a1[1]}, zero);
                acc[r] = dot2_acc(p, (f16x2){w1[0], w1[1]}, acc[r]);
                p = __builtin_elementwise_max((f16x2){t1[2] + a1[2], t1[3] + a1[3]}, zero);
                acc[r] = dot2_acc(p, (f16x2){w1[2], w1[3]}, acc[r]);
            }
            const int nx = i + PF;
            if (nx < 32) { pa[sl] = L_A0(nx); pb[sl] = L_A1(nx); }
        }
#undef L_A0
#undef L_A1
        float* dst = lp + (size_t)(hc * 256 + bt0) * 512 + a;
        #pragma unroll
        for (int r = 0; r < 4; ++r) dst[(size_t)r * 512] = acc[r];
    }
}

// ---------------------------------------------------------------------------
// combine: blocks [0,256): sum lp chunks + bias + monotonic, softmax -> out.
//          blocks [256,288): conv3 + GN2 (reduced from bstat2) + softplus.
// ---------------------------------------------------------------------------
__global__ __launch_bounds__(512) void combine_k(
    const float* __restrict__ lp, const float* __restrict__ b2,
    const bf16_t* __restrict__ y2, const float* __restrict__ bstat2,
    const float* __restrict__ g, const float* __restrict__ bet,
    const float* __restrict__ w3, const float* __restrict__ b3,
    float* __restrict__ out)
{
    __shared__ float redm[8], redsum[8];
    const int bid = blockIdx.x;
    const int tid = threadIdx.x;
    if (bid < 256) {
        const int bt = bid, t = bt & 127;
        const int a = tid;
        const int lane = a & 63, wid = a >> 6;
        const size_t base = (size_t)bt * 512 + a;
        float v = lp[base] + lp[131072 + base] + lp[262144 + base] + lp[393216 + base];
        v += b2[0] - 0.1f * fabsf((float)a - 4.0f * (float)t);
        float m = v;
        #pragma unroll
        for (int off = 32; off > 0; off >>= 1) m = fmaxf(m, __shfl_xor(m, off));
        if (lane == 0) redm[wid] = m;
        __syncthreads();
        float M = redm[0];
        #pragma unroll
        for (int i = 1; i < 8; ++i) M = fmaxf(M, redm[i]);
        const float e = expf(v - M);
        float s = e;
        #pragma unroll
        for (int off = 32; off > 0; off >>= 1) s += __shfl_xor(s, off);
        if (lane == 0) redsum[wid] = s;
        __syncthreads();
        float S = redsum[0];
        #pragma unroll
        for (int i = 1; i < 8; ++i) S += redsum[i];
        out[(size_t)bt * 512 + a] = e * (1.0f / S);
    } else {
        // conv3 + GN2-fold + softplus; mu/var reduced from conv2 partials.
        const int cb = bid - 256;              // 0..31, bt [cb*8, cb*8+8)
        const int b = (cb * 8) >> 7;
        float mu, rsig;
        reduce_bstat(bstat2, b, tid, redm, redsum, mu, rsig);
        const int lane = tid & 63, w = tid >> 6;
        const int bt = cb * 8 + w;
        const bf16_t* row = y2 + (size_t)bt * 1024 + lane * 16;
        float s1 = 0.f, s2 = 0.f, s3 = 0.f;
        #pragma unroll
        for (int c = 0; c < 2; ++c) {
            bf16x8 yv = *(const bf16x8*)(row + c * 8);
            #pragma unroll
            for (int j = 0; j < 8; ++j) {
                const int i = lane * 16 + c * 8 + j;
                const float gw = g[i] * w3[i];
                s1 += gw * (float)yv[j];
                s2 += gw;
                s3 += bet[i] * w3[i];
            }
        }
        #pragma unroll
        for (int off = 32; off > 0; off >>= 1) {
            s1 += __shfl_xor(s1, off);
            s2 += __shfl_xor(s2, off);
            s3 += __shfl_xor(s3, off);
        }
        if (lane == 0) {
            const float t = rsig * (s1 - mu * s2) + s3 + b3[0];
            out[131072 + bt] = fmaxf(t, 0.f) + log1pf(expf(-fabsf(t)));
        }
    }
}

extern "C" void kernel_launch(void* const* d_in, const int* in_sizes, int n_in,
                              void* d_out, int out_size, void* d_ws, size_t ws_size,
                              hipStream_t stream) {
    const float* text   = (const float*)d_in[0];
    const float* audio  = (const float*)d_in[1];
    const float* a_w1   = (const float*)d_in[2];
    const float* a_b1   = (const float*)d_in[3];
    const float* a_w2   = (const float*)d_in[4];
    const float* a_b2   = (const float*)d_in[5];
    const float* d_w1   = (const float*)d_in[6];
    const float* d_b1   = (const float*)d_in[7];
    const float* gn1_g  = (const float*)d_in[8];
    const float* gn1_b  = (const float*)d_in[9];
    const float* d_w2   = (const float*)d_in[10];
    const float* d_b2   = (const float*)d_in[11];
    const float* gn2_g  = (const float*)d_in[12];
    const float* gn2_b  = (const float*)d_in[13];
    const float* d_w3   = (const float*)d_in[14];
    const float* d_b3   = (const float*)d_in[15];

    char* ws = (char*)d_ws;
    float* outf = (float*)d_out;

    bf16_t* text_bf  = (bf16_t*)(ws + OFF_TEXTBF);
    bf16_t* audio_bf = (bf16_t*)(ws + OFF_AUDIOBF);
    bf16_t* w1topT   = (bf16_t*)(ws + OFF_W1TOP);
    bf16_t* w1botT   = (bf16_t*)(ws + OFF_W1BOT);
    bf16_t* wc1      = (bf16_t*)(ws + OFF_WC1);
    bf16_t* wc2      = (bf16_t*)(ws + OFF_WC2);
    f16_t*  tp       = (f16_t*) (ws + OFF_TP);
    f16_t*  w2f      = (f16_t*) (ws + OFF_W2F);
    f16_t*  apT4     = (f16_t*) (ws + OFF_APT);
    bf16_t* xp0      = (bf16_t*)(ws + OFF_XP0);
    bf16_t* xp1      = (bf16_t*)(ws + OFF_XP1);
    bf16_t* y2       = (bf16_t*)(ws + OFF_Y2);
    float*  bstat1   = (float*) (ws + OFF_BST1);
    float*  bstat2   = (float*) (ws + OFF_BST2);
    float*  lp       = (float*) (ws + OFF_LP);
    float*  Sg3     = (float*) (ws + OFF_SG);
    float*  Sb3     = (float*) (ws + OFF_SB);
    float*  SgFp    = (float*) (ws + OFF_SGF);
    float*  SbFp    = (float*) (ws + OFF_SBF);

    // 1: prep (cvt activations, w1 transpose, conv weights + sums, pads, w2f)
    prep_k<<<dim3(5377), 256, 0, stream>>>(text, audio, a_w1, d_w1, d_w2, a_w2,
                                           gn1_g, gn1_b,
                                           text_bf, xp0, audio_bf, w1topT, w1botT,
                                           wc1, wc2, xp1, w2f, Sg3, Sb3,
                                           SgFp, SbFp);
    // 2: conv1 (512) ∥ tp gemm (256) ∥ ap gemm (1024) — 1792 x 512 thr
    p2_k<<<dim3(1792), 512, 0, stream>>>(wc1, xp0, d_b1, xp1, bstat1,
                                         text_bf, w1topT, a_b1, tp,
                                         audio_bf, w1botT, apT4);
    // 3: conv2 (512, GN1 folded) ∥ logits (256) — 768 x 512 thr
    p3_k<<<dim3(768), 512, 0, stream>>>(wc2, xp1, d_b2, y2, bstat2, bstat1,
                                        SgFp, SbFp, Sg3, Sb3, tp, apT4, w2f, lp);
    // 4: combine+softmax -> alignment; conv3+GN2(reduced)+softplus -> durations
    combine_k<<<dim3(288), 512, 0, stream>>>(lp, a_b2, y2, bstat2,
                                             gn2_g, gn2_b, d_w3, d_b3, outf);
}